// Round 1
// baseline (545.624 us; speedup 1.0000x reference)
//
#include <hip/hip_runtime.h>
#include <hip/hip_bf16.h>
#include <cstdint>

#define N 4096

__device__ __forceinline__ float elu_f(float x){ return x > 0.f ? x : __expf(x) - 1.f; }

// ---------------- adj -> transposed bitmask: bitsT[word][n] ----------------
__global__ __launch_bounds__(256) void mask_kernel(const int* __restrict__ adj,
                                                   unsigned long long* __restrict__ bitsT){
  int gwave = (blockIdx.x * blockDim.x + threadIdx.x) >> 6;
  int lane = threadIdx.x & 63;
  if (gwave >= N) return;
  const int* arow = adj + (size_t)gwave * N;
  for (int w = 0; w < 64; ++w){
    unsigned long long b = __ballot(arow[(w << 6) + lane] != 0);
    if (lane == 0) bitsT[(size_t)w * N + gwave] = b;
  }
}

// ---------------- layer 1: Wh1[h][n][o] = x(128) . W_heads[h](128x64) ------
__global__ __launch_bounds__(256) void wh1_kernel(const float* __restrict__ x,
                                                  const float* __restrict__ W,
                                                  float* __restrict__ Wh){
  int n0 = blockIdx.x * 16;
  int tid = threadIdx.x;
  int h = tid >> 5;            // 8 heads
  int o = (tid & 31) * 2;      // 2 outputs per thread
  const float* Wp = W + h * 8192 + o;   // W[h][f][o], f stride 64
  float acc0[16], acc1[16];
  #pragma unroll
  for (int r = 0; r < 16; ++r){ acc0[r] = 0.f; acc1[r] = 0.f; }
  for (int f4 = 0; f4 < 32; ++f4){
    float2 wv0 = *(const float2*)(Wp + (f4*4+0)*64);
    float2 wv1 = *(const float2*)(Wp + (f4*4+1)*64);
    float2 wv2 = *(const float2*)(Wp + (f4*4+2)*64);
    float2 wv3 = *(const float2*)(Wp + (f4*4+3)*64);
    #pragma unroll
    for (int r = 0; r < 16; ++r){
      float4 xv = *(const float4*)(x + (size_t)(n0 + r)*128 + f4*4); // block-uniform
      acc0[r] += xv.x*wv0.x; acc1[r] += xv.x*wv0.y;
      acc0[r] += xv.y*wv1.x; acc1[r] += xv.y*wv1.y;
      acc0[r] += xv.z*wv2.x; acc1[r] += xv.z*wv2.y;
      acc0[r] += xv.w*wv3.x; acc1[r] += xv.w*wv3.y;
    }
  }
  #pragma unroll
  for (int r = 0; r < 16; ++r){
    float2 st; st.x = acc0[r]; st.y = acc1[r];
    *(float2*)(Wh + ((size_t)(h*N) + n0 + r)*64 + o) = st;
  }
}

// ---------------- layer 2: Wh2[n][o] = hmat(512) . W_out(512x64) -----------
__global__ __launch_bounds__(256) void wh2_kernel(const float* __restrict__ hmat,
                                                  const float* __restrict__ W,
                                                  float* __restrict__ Wh2){
  int n0 = blockIdx.x * 16;
  int tid = threadIdx.x;
  int o = tid & 63;
  int rq = tid >> 6;           // 4 rows per thread
  float acc[4] = {0.f,0.f,0.f,0.f};
  for (int f4 = 0; f4 < 128; ++f4){
    float w0 = W[(f4*4+0)*64 + o];
    float w1 = W[(f4*4+1)*64 + o];
    float w2 = W[(f4*4+2)*64 + o];
    float w3 = W[(f4*4+3)*64 + o];
    #pragma unroll
    for (int r = 0; r < 4; ++r){
      float4 xv = *(const float4*)(hmat + (size_t)(n0 + rq*4 + r)*512 + f4*4); // wave-uniform
      acc[r] += xv.x*w0 + xv.y*w1 + xv.z*w2 + xv.w*w3;
    }
  }
  #pragma unroll
  for (int r = 0; r < 4; ++r)
    Wh2[(size_t)(n0 + rq*4 + r)*64 + o] = acc[r];
}

// ---------------- f1/f2 + the 4 exp vectors per (h,n) ----------------------
__global__ __launch_bounds__(256) void fvec_kernel(const float* __restrict__ Wh,
                                                   const float* __restrict__ a,
                                                   float* __restrict__ f1v, float* __restrict__ f2v,
                                                   float* __restrict__ e1p, float* __restrict__ e1n,
                                                   float* __restrict__ e2p, float* __restrict__ e2n,
                                                   int Hn){
  int gw = (blockIdx.x * 256 + threadIdx.x) >> 6;
  int lane = threadIdx.x & 63;
  if (gw >= Hn * N) return;
  int h = gw / N;
  float v = Wh[(size_t)gw * 64 + lane];
  float a1 = a[h*128 + lane];
  float a2 = a[h*128 + 64 + lane];
  float p1 = v * a1, p2 = v * a2;
  #pragma unroll
  for (int s = 32; s; s >>= 1){ p1 += __shfl_xor(p1, s); p2 += __shfl_xor(p2, s); }
  if (lane == 0){
    f1v[gw] = p1; f2v[gw] = p2;
    e1p[gw] = __expf(p1);       e1n[gw] = __expf(0.2f * p1);
    e2p[gw] = __expf(p2);       e2n[gw] = __expf(0.2f * p2);
  }
}

// ---------------- masked-softmax aggregation (num, den) --------------------
// block = (chunk c, head h, 64-row tile t). grid = 64 * Hn * nchunks
__global__ __launch_bounds__(256) void attn_kernel(
    const float* __restrict__ Wh, const unsigned long long* __restrict__ bitsT,
    const float* __restrict__ f1v, const float* __restrict__ e1p, const float* __restrict__ e1n,
    const float* __restrict__ f2v, const float* __restrict__ e2p, const float* __restrict__ e2n,
    float* __restrict__ num, float* __restrict__ den, int Hn, int nchunks)
{
  __shared__ float WhS[64][68];
  __shared__ float wTS[64][68];
  __shared__ float f1S[64], e1pS[64], e1nS[64];
  __shared__ unsigned long long maskS[64];

  const int id = blockIdx.x;
  const int t = id & 63;
  const int rest = id >> 6;
  const int h = rest % Hn;
  const int c = rest / Hn;
  const int n0 = t << 6;
  const int mlen = N / nchunks;
  const int m0base = c * mlen;
  const int tid = threadIdx.x;

  if (tid < 64){
    int gr = h*N + n0 + tid;
    f1S[tid]  = f1v[gr];
    e1pS[tid] = e1p[gr];
    e1nS[tid] = e1n[gr];
  }

  const float* WhH  = Wh  + (size_t)h * (N*64);
  const float* f2H  = f2v + (size_t)h * N;
  const float* e2pH = e2p + (size_t)h * N;
  const float* e2nH = e2n + (size_t)h * N;

  const int wid  = tid >> 6;
  const int lane = tid & 63;
  const int rg = lane >> 4;
  const int cg = lane & 15;
  const int rbase = wid*16 + rg*4;
  const int cbase = cg*4;

  const int sj = tid >> 2;          // m index within tile (0..63)
  const int sr = (tid & 3) << 4;    // 16-row segment

  float acc[4][4];
  #pragma unroll
  for (int i2 = 0; i2 < 4; ++i2)
    #pragma unroll
    for (int j2 = 0; j2 < 4; ++j2) acc[i2][j2] = 0.f;
  float dsum[4] = {0.f,0.f,0.f,0.f};

  for (int mt = 0; mt < mlen; mt += 64){
    const int m0 = m0base + mt;
    __syncthreads();                       // previous tile fully consumed
    // stage Wh tile (64x64 f32) + mask words
    #pragma unroll
    for (int i = 0; i < 4; ++i){
      int idx2 = tid + i*256;
      int row = idx2 >> 4, q = (idx2 & 15) << 2;
      *(float4*)&WhS[row][q] = *(const float4*)(WhH + (size_t)(m0+row)*64 + q);
    }
    if (tid < 64) maskS[tid] = bitsT[(size_t)(m0 >> 6)*N + n0 + tid];
    __syncthreads();
    // build softmax-weight tile wTS[m][r] (transposed for b128 row reads)
    {
      const int m = m0 + sj;
      const float f2m = f2H[m];
      const float p2  = e2pH[m];
      const float q2  = e2nH[m];
      const unsigned long long one = 1ull;
      #pragma unroll
      for (int k4 = 0; k4 < 4; ++k4){
        float wv[4];
        #pragma unroll
        for (int k = 0; k < 4; ++k){
          const int r = sr + k4*4 + k;
          float w = 0.f;
          if ((maskS[r] >> sj) & one)
            w = (f1S[r] + f2m > 0.f) ? e1pS[r]*p2 : e1nS[r]*q2;
          wv[k] = w;
        }
        float4 st; st.x = wv[0]; st.y = wv[1]; st.z = wv[2]; st.w = wv[3];
        *(float4*)&wTS[sj][sr + k4*4] = st;
      }
    }
    __syncthreads();
    // accumulate: each lane 4 rows x 4 cols
    #pragma unroll 8
    for (int j = 0; j < 64; ++j){
      const float4 wq = *(const float4*)&wTS[j][rbase];
      const float4 hq = *(const float4*)&WhS[j][cbase];
      const float wa[4] = {wq.x, wq.y, wq.z, wq.w};
      const float ha[4] = {hq.x, hq.y, hq.z, hq.w};
      #pragma unroll
      for (int i2 = 0; i2 < 4; ++i2){
        dsum[i2] += wa[i2];
        #pragma unroll
        for (int j2 = 0; j2 < 4; ++j2) acc[i2][j2] += wa[i2]*ha[j2];
      }
    }
  }

  float* nb = num + ((size_t)(c*Hn + h)*N + n0)*64;
  #pragma unroll
  for (int i2 = 0; i2 < 4; ++i2){
    float4 st; st.x = acc[i2][0]; st.y = acc[i2][1]; st.z = acc[i2][2]; st.w = acc[i2][3];
    *(float4*)(nb + (size_t)(rbase + i2)*64 + cbase) = st;
  }
  if (cg == 0){
    float* db = den + (size_t)(c*Hn + h)*N + n0;
    #pragma unroll
    for (int i2 = 0; i2 < 4; ++i2) db[rbase + i2] = dsum[i2];
  }
}

// ---------------- finalize layer 1: hmat[n][h*64+o] = elu(num/den) ---------
__global__ __launch_bounds__(256) void fin1_kernel(const float* __restrict__ num,
                                                   const float* __restrict__ den,
                                                   float* __restrict__ hmat){
  int idx = blockIdx.x * 256 + threadIdx.x;     // over 8*N*64
  int o = idx & 63;
  int hn = idx >> 6;
  int n = hn & (N - 1);
  int h = hn >> 12;
  float v = num[idx] / den[hn];
  hmat[(size_t)n*512 + h*64 + o] = elu_f(v);
}

// ---------------- finalize layer 2: out = elu(sum num / sum den) -----------
__global__ __launch_bounds__(256) void fin2_kernel(const float* __restrict__ num,
                                                   const float* __restrict__ den,
                                                   float* __restrict__ out){
  int idx = blockIdx.x * 256 + threadIdx.x;     // over N*64
  int n = idx >> 6;
  float s = 0.f, d = 0.f;
  #pragma unroll
  for (int cc = 0; cc < 8; ++cc){ s += num[idx + cc*(N*64)]; d += den[n + cc*N]; }
  out[idx] = elu_f(s / d);
}

extern "C" void kernel_launch(void* const* d_in, const int* in_sizes, int n_in,
                              void* d_out, int out_size, void* d_ws, size_t ws_size,
                              hipStream_t stream){
  const float* x       = (const float*)d_in[0];
  const int*   adj     = (const int*)d_in[1];
  // d_in[2] observation: unused by the reference
  const float* W_heads = (const float*)d_in[3];
  const float* a_heads = (const float*)d_in[4];
  const float* W_out   = (const float*)d_in[5];
  const float* a_out   = (const float*)d_in[6];
  float* out = (float*)d_out;
  char* ws = (char*)d_ws;

  const size_t MB = 1u << 20;
  unsigned long long* bitsT = (unsigned long long*)(ws + 0);     // 2 MB
  float* Wh1  = (float*)(ws + 2*MB);                             // 8 MB
  float* ev1  = (float*)(ws + 10*MB);                            // 6 x 128 KB
  float* hmat = (float*)(ws + 11*MB);                            // 8 MB
  float* Wh2  = (float*)(ws + 19*MB);                            // 1 MB
  float* ev2  = (float*)(ws + 20*MB);                            // 6 x 16 KB
  float* num1 = (float*)(ws + 21*MB);                            // 8 MB
  float* den1 = (float*)(ws + 29*MB);                            // 128 KB
  float* num2 = (float*)(ws + 30*MB);                            // 8 MB (8 chunks)
  float* den2 = (float*)(ws + 38*MB);                            // 128 KB

  const int HN1 = 8 * N;
  float *f1v1 = ev1, *f2v1 = ev1 + HN1, *e1p1 = ev1 + 2*HN1, *e1n1 = ev1 + 3*HN1,
        *e2p1 = ev1 + 4*HN1, *e2n1 = ev1 + 5*HN1;
  float *f1v2 = ev2, *f2v2 = ev2 + N, *e1p2 = ev2 + 2*N, *e1n2 = ev2 + 3*N,
        *e2p2 = ev2 + 4*N, *e2n2 = ev2 + 5*N;

  mask_kernel<<<1024, 256, 0, stream>>>(adj, bitsT);
  wh1_kernel<<<256, 256, 0, stream>>>(x, W_heads, Wh1);
  fvec_kernel<<<8192, 256, 0, stream>>>(Wh1, a_heads, f1v1, f2v1, e1p1, e1n1, e2p1, e2n1, 8);
  attn_kernel<<<512, 256, 0, stream>>>(Wh1, bitsT, f1v1, e1p1, e1n1, f2v1, e2p1, e2n1,
                                       num1, den1, 8, 1);
  fin1_kernel<<<8192, 256, 0, stream>>>(num1, den1, hmat);
  wh2_kernel<<<256, 256, 0, stream>>>(hmat, W_out, Wh2);
  fvec_kernel<<<1024, 256, 0, stream>>>(Wh2, a_out, f1v2, f2v2, e1p2, e1n2, e2p2, e2n2, 1);
  attn_kernel<<<512, 256, 0, stream>>>(Wh2, bitsT, f1v2, e1p2, e1n2, f2v2, e2p2, e2n2,
                                       num2, den2, 1, 8);
  fin2_kernel<<<1024, 256, 0, stream>>>(num2, den2, out);
}

// Round 2
// 158.227 us; speedup vs baseline: 3.4484x; 3.4484x over previous
//
#include <hip/hip_runtime.h>
#include <hip/hip_bf16.h>
#include <cstdint>

#define N 4096
#define L2E 1.44269504088896f

typedef __attribute__((ext_vector_type(8))) short bf16x8;
typedef __attribute__((ext_vector_type(4))) float f32x4;

__device__ __forceinline__ float elu_f(float x){ return x > 0.f ? x : __expf(x) - 1.f; }
__device__ __forceinline__ short bfc(float x){
  __hip_bfloat16 h = __float2bfloat16(x);
  return *reinterpret_cast<short*>(&h);
}

// ---------------- adj -> transposed bitmask: bitsT[word][n] ----------------
__global__ __launch_bounds__(256) void mask_kernel(const int* __restrict__ adj,
                                                   unsigned long long* __restrict__ bitsT){
  int gwave = (blockIdx.x * blockDim.x + threadIdx.x) >> 6;
  int lane = threadIdx.x & 63;
  if (gwave >= N) return;
  const int* arow = adj + (size_t)gwave * N;
  for (int w = 0; w < 64; ++w){
    unsigned long long b = __ballot(arow[(w << 6) + lane] != 0);
    if (lane == 0) bitsT[(size_t)w * N + gwave] = b;
  }
}

// ---------------- layer 1: Wh1[h][n][o] = x(128) . W_heads[h](128x64) ------
__global__ __launch_bounds__(256) void wh1_kernel(const float* __restrict__ x,
                                                  const float* __restrict__ W,
                                                  float* __restrict__ Wh){
  int n0 = blockIdx.x * 16;
  int tid = threadIdx.x;
  int h = tid >> 5;
  int o = (tid & 31) * 2;
  const float* Wp = W + h * 8192 + o;
  float acc0[16], acc1[16];
  #pragma unroll
  for (int r = 0; r < 16; ++r){ acc0[r] = 0.f; acc1[r] = 0.f; }
  for (int f4 = 0; f4 < 32; ++f4){
    float2 wv0 = *(const float2*)(Wp + (f4*4+0)*64);
    float2 wv1 = *(const float2*)(Wp + (f4*4+1)*64);
    float2 wv2 = *(const float2*)(Wp + (f4*4+2)*64);
    float2 wv3 = *(const float2*)(Wp + (f4*4+3)*64);
    #pragma unroll
    for (int r = 0; r < 16; ++r){
      float4 xv = *(const float4*)(x + (size_t)(n0 + r)*128 + f4*4);
      acc0[r] += xv.x*wv0.x; acc1[r] += xv.x*wv0.y;
      acc0[r] += xv.y*wv1.x; acc1[r] += xv.y*wv1.y;
      acc0[r] += xv.z*wv2.x; acc1[r] += xv.z*wv2.y;
      acc0[r] += xv.w*wv3.x; acc1[r] += xv.w*wv3.y;
    }
  }
  #pragma unroll
  for (int r = 0; r < 16; ++r){
    float2 st; st.x = acc0[r]; st.y = acc1[r];
    *(float2*)(Wh + ((size_t)(h*N) + n0 + r)*64 + o) = st;
  }
}

// ---------------- layer 2: Wh2[n][o] = hmat(512) . W_out(512x64) -----------
__global__ __launch_bounds__(256) void wh2_kernel(const float* __restrict__ hmat,
                                                  const float* __restrict__ W,
                                                  float* __restrict__ Wh2){
  int n0 = blockIdx.x * 16;
  int tid = threadIdx.x;
  int o = tid & 63;
  int rq = tid >> 6;
  float acc[4] = {0.f,0.f,0.f,0.f};
  for (int f4 = 0; f4 < 128; ++f4){
    float w0 = W[(f4*4+0)*64 + o];
    float w1 = W[(f4*4+1)*64 + o];
    float w2 = W[(f4*4+2)*64 + o];
    float w3 = W[(f4*4+3)*64 + o];
    #pragma unroll
    for (int r = 0; r < 4; ++r){
      float4 xv = *(const float4*)(hmat + (size_t)(n0 + rq*4 + r)*512 + f4*4);
      acc[r] += xv.x*w0 + xv.y*w1 + xv.z*w2 + xv.w*w3;
    }
  }
  #pragma unroll
  for (int r = 0; r < 4; ++r)
    Wh2[(size_t)(n0 + rq*4 + r)*64 + o] = acc[r];
}

// ---------------- f1/f2 per (h,n), pre-scaled by log2(e) -------------------
__global__ __launch_bounds__(256) void fvec_kernel(const float* __restrict__ Wh,
                                                   const float* __restrict__ a,
                                                   float* __restrict__ f1v, float* __restrict__ f2v,
                                                   int Hn){
  int gw = (blockIdx.x * 256 + threadIdx.x) >> 6;
  int lane = threadIdx.x & 63;
  if (gw >= Hn * N) return;
  int h = gw >> 12;
  float v = Wh[(size_t)gw * 64 + lane];
  float a1 = a[h*128 + lane];
  float a2 = a[h*128 + 64 + lane];
  float p1 = v * a1, p2 = v * a2;
  #pragma unroll
  for (int s = 32; s; s >>= 1){ p1 += __shfl_xor(p1, s); p2 += __shfl_xor(p2, s); }
  if (lane == 0){
    f1v[gw] = p1 * L2E;
    f2v[gw] = p2 * L2E;
  }
}

// ---------------- transpose + bf16: WhT[h][o][n] = bf16(Wh[h][n][o]) -------
__global__ __launch_bounds__(256) void trans_kernel(const float* __restrict__ Wh,
                                                    ushort* __restrict__ WhT){
  __shared__ float T[64][65];
  int h = blockIdx.x >> 6;
  int n0 = (blockIdx.x & 63) * 64;
  const float* src = Wh + ((size_t)h*N + n0)*64;
  #pragma unroll
  for (int i = 0; i < 16; ++i){
    int idx = threadIdx.x + i*256;
    T[idx >> 6][idx & 63] = src[idx];
  }
  __syncthreads();
  int o = threadIdx.x >> 2;
  int nq = (threadIdx.x & 3) * 16;
  ushort tmp[16];
  #pragma unroll
  for (int j = 0; j < 16; ++j) tmp[j] = (ushort)bfc(T[nq + j][o]);
  ushort* dst = WhT + ((size_t)(h*64 + o))*N + n0 + nq;
  *(int4*)dst = *(int4*)&tmp[0];
  *(int4*)(dst + 8) = *(int4*)&tmp[8];
}

// ---------------- MFMA masked-softmax aggregation --------------------------
// block = 256 thr (4 waves), output 64 n x 64 o per (h, tile, chunk)
__global__ __launch_bounds__(256) void attn_mfma_kernel(
    const ushort* __restrict__ WhT, const unsigned long long* __restrict__ bitsT,
    const float* __restrict__ f1v, const float* __restrict__ f2v,
    float* __restrict__ num, float* __restrict__ den, int Hn, int nchunks)
{
  __shared__ ushort BT[64][72];   // padded: row stride 144B (16B-aligned, ~2-way banks)
  const int t    = blockIdx.x & 63;
  const int rest = blockIdx.x >> 6;
  const int h    = rest % Hn;
  const int c    = rest / Hn;
  const int n0   = t << 6;
  const int mlen = N / nchunks;
  const int m0b  = c * mlen;
  const int tid  = threadIdx.x;
  const int w    = tid >> 6;
  const int l    = tid & 63;
  const int r16  = l & 15;
  const int kg   = l >> 4;
  const int n    = n0 + w*16 + r16;

  const float f1r = f1v[h*N + n];
  const ushort* Wb = WhT + (size_t)h * 64 * N;
  const float* f2H = f2v + h*N;
  const unsigned long long* mrow = bitsT + n;

  const int sr0 = tid >> 3;          // staging: rows 0..31 (+32 for second)
  const int sq0 = (tid & 7) * 8;     // 8-bf16 chunk within row

  f32x4 acc[4] = {{0,0,0,0},{0,0,0,0},{0,0,0,0},{0,0,0,0}};
  float dacc = 0.f;

  for (int mt = 0; mt < mlen; mt += 64){
    const int m0 = m0b + mt;
    __syncthreads();                 // previous tile's B reads complete
    // ---- stage Wh tile (transposed bf16, 64 o x 64 m) ----
    {
      int4 v0 = *(const int4*)(Wb + (size_t)sr0*N + m0 + sq0);
      int4 v1 = *(const int4*)(Wb + (size_t)(sr0+32)*N + m0 + sq0);
      *(int4*)&BT[sr0][sq0] = v0;
      *(int4*)&BT[sr0+32][sq0] = v1;
    }
    // ---- build A fragments in registers (16 weights per lane) ----
    unsigned long long mw = mrow[(size_t)(m0 >> 6) * N];
    uint32_t mlo = (uint32_t)(mw >> (kg*8));
    uint32_t mhi = (uint32_t)(mw >> (kg*8 + 32));
    f32x4 fA = *(const f32x4*)(f2H + m0 + kg*8);
    f32x4 fB = *(const f32x4*)(f2H + m0 + kg*8 + 4);
    f32x4 fC = *(const f32x4*)(f2H + m0 + 32 + kg*8);
    f32x4 fD = *(const f32x4*)(f2H + m0 + 36 + kg*8);
    float wv[16];
    #pragma unroll
    for (int j = 0; j < 4; ++j){
      float s0 = f1r + fA[j];
      float s1 = f1r + fB[j];
      float s2 = f1r + fC[j];
      float s3 = f1r + fD[j];
      float e0 = __builtin_amdgcn_exp2f(fmaxf(s0, 0.2f*s0));
      float e1 = __builtin_amdgcn_exp2f(fmaxf(s1, 0.2f*s1));
      float e2 = __builtin_amdgcn_exp2f(fmaxf(s2, 0.2f*s2));
      float e3 = __builtin_amdgcn_exp2f(fmaxf(s3, 0.2f*s3));
      wv[j]      = ((mlo >> j) & 1)       ? e0 : 0.f;
      wv[4 + j]  = ((mlo >> (4 + j)) & 1) ? e1 : 0.f;
      wv[8 + j]  = ((mhi >> j) & 1)       ? e2 : 0.f;
      wv[12 + j] = ((mhi >> (4 + j)) & 1) ? e3 : 0.f;
    }
    #pragma unroll
    for (int j = 0; j < 16; ++j) dacc += wv[j];
    bf16x8 A0, A1;
    #pragma unroll
    for (int j = 0; j < 8; ++j){ A0[j] = bfc(wv[j]); A1[j] = bfc(wv[8 + j]); }
    __syncthreads();                 // BT visible
    // ---- MFMA: 4 col-subtiles x 2 k-tiles ----
    #pragma unroll
    for (int c4 = 0; c4 < 4; ++c4){
      const int col = c4*16 + r16;
      bf16x8 B0 = *(const bf16x8*)&BT[col][kg*8];
      bf16x8 B1 = *(const bf16x8*)&BT[col][32 + kg*8];
      acc[c4] = __builtin_amdgcn_mfma_f32_16x16x32_bf16(A0, B0, acc[c4], 0, 0, 0);
      acc[c4] = __builtin_amdgcn_mfma_f32_16x16x32_bf16(A1, B1, acc[c4], 0, 0, 0);
    }
  }

  // den: sum over the 4 k-groups sharing a row
  dacc += __shfl_xor(dacc, 16);
  dacc += __shfl_xor(dacc, 32);
  if (l < 16) den[(size_t)(c*Hn + h)*N + n] = dacc;

  float* nb = num + ((size_t)(c*Hn + h)*N + n0 + w*16)*64;
  #pragma unroll
  for (int c4 = 0; c4 < 4; ++c4){
    #pragma unroll
    for (int r = 0; r < 4; ++r)
      nb[(size_t)(kg*4 + r)*64 + c4*16 + r16] = acc[c4][r];
  }
}

// ---------------- finalize layer 1 (2 chunks): hmat = elu(num/den) ---------
__global__ __launch_bounds__(256) void fin1_kernel(const float* __restrict__ num,
                                                   const float* __restrict__ den,
                                                   float* __restrict__ hmat){
  int idx = blockIdx.x * 256 + threadIdx.x;     // over 8*N*64
  int o = idx & 63;
  int hn = idx >> 6;
  int n = hn & (N - 1);
  int h = hn >> 12;
  float nu = num[idx] + num[idx + 8*N*64];
  float de = den[hn] + den[hn + 8*N];
  hmat[(size_t)n*512 + h*64 + o] = elu_f(nu / de);
}

// ---------------- finalize layer 2 (8 chunks): out = elu(sum/sum) ----------
__global__ __launch_bounds__(256) void fin2_kernel(const float* __restrict__ num,
                                                   const float* __restrict__ den,
                                                   float* __restrict__ out){
  int idx = blockIdx.x * 256 + threadIdx.x;     // over N*64
  int n = idx >> 6;
  float s = 0.f, d = 0.f;
  #pragma unroll
  for (int cc = 0; cc < 8; ++cc){ s += num[idx + cc*(N*64)]; d += den[n + cc*N]; }
  out[idx] = elu_f(s / d);
}

extern "C" void kernel_launch(void* const* d_in, const int* in_sizes, int n_in,
                              void* d_out, int out_size, void* d_ws, size_t ws_size,
                              hipStream_t stream){
  const float* x       = (const float*)d_in[0];
  const int*   adj     = (const int*)d_in[1];
  const float* W_heads = (const float*)d_in[3];
  const float* a_heads = (const float*)d_in[4];
  const float* W_out   = (const float*)d_in[5];
  const float* a_out   = (const float*)d_in[6];
  float* out = (float*)d_out;
  char* ws = (char*)d_ws;

  const size_t MB = 1u << 20;
  unsigned long long* bitsT = (unsigned long long*)(ws);         // 2 MB
  float*  Wh1f = (float*)(ws + 2*MB);                            // 8 MB (reused as hmat)
  ushort* Wh1T = (ushort*)(ws + 10*MB);                          // 4 MB
  float*  f1v1 = (float*)(ws + 14*MB);                           // 128 KB
  float*  f2v1 = (float*)(ws + 14*MB + 128*1024);                // 128 KB
  float*  den1 = (float*)(ws + 14*MB + 256*1024);                // 256 KB (2 chunks)
  float*  num1 = (float*)(ws + 15*MB);                           // 16 MB (2 chunks)
  float*  hmat = Wh1f;                                           // reuse 2..10 MB
  float*  Wh2f = (float*)(ws + 31*MB);                           // 1 MB
  ushort* Wh2T = (ushort*)(ws + 32*MB);                          // 0.5 MB
  float*  f1v2 = (float*)(ws + 32*MB + 512*1024);                // 16 KB
  float*  f2v2 = (float*)(ws + 32*MB + 528*1024);                // 16 KB
  float*  den2 = (float*)(ws + 33*MB);                           // 128 KB (8 chunks)
  float*  num2 = num1;                                           // reuse 15..23 MB (8 chunks)

  mask_kernel<<<1024, 256, 0, stream>>>(adj, bitsT);
  wh1_kernel<<<256, 256, 0, stream>>>(x, W_heads, Wh1f);
  fvec_kernel<<<8192, 256, 0, stream>>>(Wh1f, a_heads, f1v1, f2v1, 8);
  trans_kernel<<<512, 256, 0, stream>>>(Wh1f, Wh1T);
  attn_mfma_kernel<<<1024, 256, 0, stream>>>(Wh1T, bitsT, f1v1, f2v1, num1, den1, 8, 2);
  fin1_kernel<<<8192, 256, 0, stream>>>(num1, den1, hmat);
  wh2_kernel<<<256, 256, 0, stream>>>(hmat, W_out, Wh2f);
  fvec_kernel<<<1024, 256, 0, stream>>>(Wh2f, a_out, f1v2, f2v2, 1);
  trans_kernel<<<64, 256, 0, stream>>>(Wh2f, Wh2T);
  attn_mfma_kernel<<<512, 256, 0, stream>>>(Wh2T, bitsT, f1v2, f2v2, num2, den2, 1, 8);
  fin2_kernel<<<1024, 256, 0, stream>>>(num2, den2, out);
}